// Round 16
// baseline (669.719 us; speedup 1.0000x reference)
//
#include <hip/hip_runtime.h>
#include <cstdint>
#include <cstddef>

#define ND 8000
#define NL 16000
#define NE 60000
#define NM 50000

typedef __attribute__((ext_vector_type(8))) short bf16x8;
typedef __attribute__((ext_vector_type(4))) float f32x4;
typedef __attribute__((ext_vector_type(8))) unsigned int u32x8;

__device__ __forceinline__ unsigned short f2bf(float x) {
    unsigned int u = __float_as_uint(x);
    unsigned int r = (u + 0x7FFFu + ((u >> 16) & 1u)) >> 16;
    return (unsigned short)r;
}
__device__ __forceinline__ float bf2f(unsigned short b) {
    return __uint_as_float(((unsigned int)b) << 16);
}
__device__ __forceinline__ float lrelu(float x) {
    return x >= 0.f ? x : 0.2f * x;
}

// ---------------- input-linear weight pack: split-bf16 B-fragments, K zero-padded ------
__global__ void wtin_kernel(const float* __restrict__ Wd, const float* __restrict__ Wl,
                            unsigned short* __restrict__ WinH, unsigned short* __restrict__ WinL)
{
    int gid = blockIdx.x * 256 + threadIdx.x;
    if (gid >= 53248 + 32768) return;
    const float* W; int K, KC; unsigned short* oH; unsigned short* oL; int rem;
    if (gid < 53248) { W = Wd; K = 412; KC = 13; rem = gid; oH = WinH; oL = WinL; }
    else { W = Wl; K = 240; KC = 8; rem = gid - 53248; oH = WinH + 53248; oL = WinL + 53248; }
    int k = rem >> 7, n = rem & 127;
    float v = (k < K) ? W[(size_t)k * 128 + n] : 0.f;
    unsigned short hb = f2bf(v);
    unsigned short lb = f2bf(v - bf2f(hb));
    int u = n >> 4;
    int kc = k >> 5;
    int lane = (n & 15) + 16 * ((k >> 3) & 3);
    size_t o = ((size_t)u * KC + kc) * 512 + lane * 8 + (k & 7);
    oH[o] = hb;
    oL[o] = lb;
}

// ---------------- fused input linears via split-bf16 MFMA (direct A loads) -------------
__global__ __launch_bounds__(256) void inlinm_kernel(
    const float* __restrict__ x_d, const float* __restrict__ x_l,
    const unsigned short* __restrict__ WinH, const unsigned short* __restrict__ WinL,
    const float* __restrict__ bd, const float* __restrict__ bl,
    const float* __restrict__ embd, const float* __restrict__ embl,
    const int* __restrict__ nidd, const int* __restrict__ nidl,
    float* __restrict__ hd, float* __restrict__ hl)
{
    const int tid = threadIdx.x;
    const int wave = tid >> 6;
    const int lane = tid & 63;
    const int i = blockIdx.x;
    const int cb = i & 1;
    int mt = i >> 1;
    const float* X; int K, KC;
    const unsigned short* wH; const unsigned short* wL;
    const float* bias; const float* emb; const int* nid; float* out;
    if (mt < 125) {
        X = x_d; K = 412; KC = 13; wH = WinH; wL = WinL;
        bias = bd; emb = embd; nid = nidd; out = hd;
    } else {
        mt -= 125;
        X = x_l; K = 240; KC = 8; wH = WinH + 53248; wL = WinL + 53248;
        bias = bl; emb = embl; nid = nidl; out = hl;
    }
    const int m0 = mt * 64 + wave * 16;
    const int row = lane & 15;
    const int quad = lane >> 4;

    f32x4 accH[4] = {};
    f32x4 accL[4] = {};

    const float* xr = X + (size_t)(m0 + row) * K;
    for (int kc = 0; kc < KC; ++kc) {
        int k0 = kc * 32 + quad * 8;
        float xv[8];
        if (k0 + 8 <= K) {
            float4 v0 = *(const float4*)(xr + k0);
            float4 v1 = *(const float4*)(xr + k0 + 4);
            xv[0] = v0.x; xv[1] = v0.y; xv[2] = v0.z; xv[3] = v0.w;
            xv[4] = v1.x; xv[5] = v1.y; xv[6] = v1.z; xv[7] = v1.w;
        } else {
#pragma unroll
            for (int j = 0; j < 8; ++j)
                xv[j] = (k0 + j < K) ? xr[k0 + j] : 0.f;
        }
        bf16x8 aH, aL;
#pragma unroll
        for (int j = 0; j < 8; ++j) {
            unsigned short hb = f2bf(xv[j]);
            aH[j] = (short)hb;
            aL[j] = (short)f2bf(xv[j] - bf2f(hb));
        }
#pragma unroll
        for (int u = 0; u < 4; ++u) {
            int ug = cb * 4 + u;
            size_t boff = ((size_t)ug * KC + kc) * 512 + lane * 8;
            bf16x8 bH = *(const bf16x8*)(wH + boff);
            bf16x8 bL = *(const bf16x8*)(wL + boff);
            accH[u] = __builtin_amdgcn_mfma_f32_16x16x32_bf16(aH, bH, accH[u], 0, 0, 0);
            accL[u] = __builtin_amdgcn_mfma_f32_16x16x32_bf16(aH, bL, accL[u], 0, 0, 0);
            accL[u] = __builtin_amdgcn_mfma_f32_16x16x32_bf16(aL, bH, accL[u], 0, 0, 0);
        }
    }
#pragma unroll
    for (int r = 0; r < 4; ++r) {
        int gm = m0 + quad * 4 + r;
        const float* ep = emb + (size_t)nid[gm] * 128;
        float* op = out + (size_t)gm * 128;
#pragma unroll
        for (int u = 0; u < 4; ++u) {
            int gn = (cb * 4 + u) * 16 + row;
            op[gn] = accH[u][r] + accL[u][r] + bias[gn] + ep[gn];
        }
    }
}

// ---------------- W transpose + split-bf16 into MFMA-fragment tiling, layers 1-2 -------
__global__ void wt2_kernel(const float* __restrict__ W0, const float* __restrict__ W1,
                           unsigned short* __restrict__ WtH, unsigned short* __restrict__ WtL)
{
    int gid = blockIdx.x * 256 + threadIdx.x;
    if (gid >= 2 * 2 * 128 * 2048) return;
    int l = gid >> 19;
    int rem0 = gid & 524287;
    int dir = rem0 >> 18;
    int rem = rem0 & 262143;
    int k = rem >> 11, n = rem & 2047;
    const float* W = l ? W1 : W0;
    float v = W[(size_t)dir * 262144 + (size_t)k * 2048 + n];
    unsigned short hb = f2bf(v);
    unsigned short lb = f2bf(v - bf2f(hb));
    int u = n >> 4;
    int lane = (n & 15) + 16 * ((k >> 3) & 3);
    size_t o = (size_t)l * 524288 + (size_t)dir * 262144 +
               ((size_t)u * 4 + (k >> 5)) * 512 + lane * 8 + (k & 7);
    WtH[o] = hb;
    WtL[o] = lb;
}

// ---------------- W3 split-bf16 fragment pack (layer 3, [2,128,512]) -------------------
__global__ void wt3_kernel(const float* __restrict__ W3,
                           unsigned short* __restrict__ WtH3, unsigned short* __restrict__ WtL3)
{
    int gid = blockIdx.x * 256 + threadIdx.x;
    if (gid >= 2 * 128 * 512) return;
    int dir = gid >> 16;
    int rem = gid & 65535;
    int k = rem >> 9, n = rem & 511;
    float v = W3[(size_t)dir * 65536 + (size_t)k * 512 + n];
    unsigned short hb = f2bf(v);
    unsigned short lb = f2bf(v - bf2f(hb));
    int u = n >> 4;
    int lane = (n & 15) + 16 * ((k >> 3) & 3);
    size_t o = (size_t)dir * 65536 + ((size_t)u * 4 + (k >> 5)) * 512 + lane * 8 + (k & 7);
    WtH3[o] = hb;
    WtL3[o] = lb;
}

// ---------------- pack hd/hl (fp32 [M,128]) -> split-bf16 A-fragment layout ------------
__global__ void pack3_kernel(const float* __restrict__ hd, const float* __restrict__ hl,
                             unsigned int* __restrict__ pAd, unsigned int* __restrict__ pAl)
{
    int gid = blockIdx.x * 256 + threadIdx.x;
    if (gid >= (ND + NL) * 128) return;
    int row = gid >> 7, k = gid & 127;
    const float* src; unsigned int* dst; int gm;
    if (row < ND) { src = hd; dst = pAd; gm = row; }
    else { src = hl; dst = pAl; gm = row - ND; }
    float v = src[(size_t)gm * 128 + k];
    unsigned short hb = f2bf(v);
    unsigned short lb = f2bf(v - bf2f(hb));
    int t = gm >> 4;
    int lane8 = ((gm & 15) + 16 * ((k >> 3) & 3)) * 8 + (k & 7);
    size_t idx = ((size_t)t * 4 + (k >> 5)) * 512 + lane8;
    dst[idx] = (unsigned int)hb | ((unsigned int)lb << 16);
}

// ---------------- layer-3 GEMM via split-bf16 MFMA: zs = h @ W3 ------------------------
__global__ __launch_bounds__(256) void gemm3m_kernel(
    const unsigned int* __restrict__ pAd, const unsigned int* __restrict__ pAl,
    const unsigned short* __restrict__ WtH3, const unsigned short* __restrict__ WtL3,
    float* __restrict__ zs3d, float* __restrict__ zs3l)
{
    const int tid = threadIdx.x;
    const int wave = tid >> 6;
    const int lane = tid & 63;
    const int cb = blockIdx.x & 1;
    int mt = blockIdx.x >> 1;
    const unsigned int* pA_; const unsigned short* wH; const unsigned short* wL; float* zs;
    if (mt < 125) { pA_ = pAd; wH = WtH3; wL = WtL3; zs = zs3d; }
    else { mt -= 125; pA_ = pAl; wH = WtH3 + 65536; wL = WtL3 + 65536; zs = zs3l; }
    const int m0 = mt * 64 + wave * 16;
    const int t = m0 >> 4;
    const int row = lane & 15;
    const int quad = lane >> 4;

    bf16x8 aH[4], aL[4];
#pragma unroll
    for (int kc = 0; kc < 4; ++kc) {
        u32x8 p = *(const u32x8*)(pA_ + ((size_t)t * 4 + kc) * 512 + lane * 8);
#pragma unroll
        for (int ii = 0; ii < 8; ++ii) {
            aH[kc][ii] = (short)(p[ii] & 0xffffu);
            aL[kc][ii] = (short)(p[ii] >> 16);
        }
    }

#pragma unroll 2
    for (int u = 0; u < 16; ++u) {
        const int ug = cb * 16 + u;
        f32x4 accH = (f32x4){0.f, 0.f, 0.f, 0.f};
        f32x4 accL = (f32x4){0.f, 0.f, 0.f, 0.f};
#pragma unroll
        for (int kc = 0; kc < 4; ++kc) {
            size_t boff = ((size_t)ug * 4 + kc) * 512 + lane * 8;
            bf16x8 bH = *(const bf16x8*)(wH + boff);
            bf16x8 bL = *(const bf16x8*)(wL + boff);
            accH = __builtin_amdgcn_mfma_f32_16x16x32_bf16(aH[kc], bH, accH, 0, 0, 0);
            accL = __builtin_amdgcn_mfma_f32_16x16x32_bf16(aH[kc], bL, accL, 0, 0, 0);
            accL = __builtin_amdgcn_mfma_f32_16x16x32_bf16(aL[kc], bH, accL, 0, 0, 0);
        }
        const int gn = ug * 16 + row;
#pragma unroll
        for (int r = 0; r < 4; ++r) {
            int gm = m0 + quad * 4 + r;
            zs[(size_t)gm * 512 + gn] = accH[r] + accL[r];
        }
    }
}

// ---------------- fused per-head projection + bias + relu + HEAD-MEAN (layers 1-2) ----
// v9: ZERO LDS, ZERO BARRIERS. Every variant with the stage->barrier-per-h structure
// (v2/v5/v6/v8) landed at ~65-70us regardless of conflicts/unpack/operand choice -- the
// invariant was the per-h vmcnt(0)+barrier drain. Here each wave is fully independent:
// wave = (16-row tile) x (column half); A fragments loaded per-wave from global (u32x8
// at lane*32B, the v2-validated pattern), prefetched one h ahead; B streamed from L2
// (4 MB resident). Wave-pairs in a block share the A tile via L1. 3000 waves free-run.
__global__ __launch_bounds__(256) void gemm2r_kernel(
    const unsigned int* __restrict__ haggPl, const unsigned int* __restrict__ haggPd,
    const unsigned short* __restrict__ WtHb, const unsigned short* __restrict__ WtLb,
    const float* __restrict__ biasb, float* __restrict__ outl, float* __restrict__ outd)
{
    const int tid = threadIdx.x;
    const int wave = tid >> 6;
    const int lane = tid & 63;
    int item = blockIdx.x * 4 + wave;

    const unsigned int* haggP; const unsigned short* wHb; const unsigned short* wLb;
    const float* bias; float* out; int t, cb;
    if (item < 2000) {             // NL: 1000 tiles x 2 col-halves
        t = item >> 1; cb = item & 1;
        haggP = haggPl; wHb = WtHb; wLb = WtLb; bias = biasb; out = outl;
    } else {                       // ND: 500 tiles x 2 col-halves
        item -= 2000;
        t = item >> 1; cb = item & 1;
        haggP = haggPd; wHb = WtHb + 262144; wLb = WtLb + 262144;
        bias = biasb + 2048; out = outd;
    }
    const int row = lane & 15;
    const int quad = lane >> 4;

    // prefetch h=0 A fragments (packed u32: lo=H, hi=L)
    u32x8 pA[4];
#pragma unroll
    for (int kc = 0; kc < 4; ++kc)
        pA[kc] = *(const u32x8*)(haggP + (((size_t)t * 16 + 0) * 4 + kc) * 512 + lane * 8);

    f32x4 mean[4] = {};

    for (int h = 0; h < 16; ++h) {
        // unpack current h's A (frees pA for next prefetch)
        bf16x8 aH[4], aL[4];
#pragma unroll
        for (int kc = 0; kc < 4; ++kc) {
#pragma unroll
            for (int ii = 0; ii < 8; ++ii) {
                aH[kc][ii] = (short)(pA[kc][ii] & 0xffffu);
                aL[kc][ii] = (short)(pA[kc][ii] >> 16);
            }
        }
        // prefetch next h's A into registers (latency hidden under this h's MFMAs)
        if (h < 15) {
#pragma unroll
            for (int kc = 0; kc < 4; ++kc)
                pA[kc] = *(const u32x8*)(haggP + (((size_t)t * 16 + h + 1) * 4 + kc) * 512 + lane * 8);
        }

        // compute this wave's column half (4 u-tiles): B streamed from L2
#pragma unroll
        for (int ctl = 0; ctl < 4; ++ctl) {
            const int u = h * 8 + cb * 4 + ctl;
            float bv = bias[h * 128 + cb * 64 + ctl * 16 + row];
            f32x4 accH = (f32x4){bv, bv, bv, bv};
            f32x4 accL = (f32x4){0.f, 0.f, 0.f, 0.f};
#pragma unroll
            for (int kc = 0; kc < 4; ++kc) {
                size_t boff = ((size_t)u * 4 + kc) * 512 + lane * 8;
                bf16x8 bH = *(const bf16x8*)(wHb + boff);
                bf16x8 bL = *(const bf16x8*)(wLb + boff);
                accH = __builtin_amdgcn_mfma_f32_16x16x32_bf16(aH[kc], bH, accH, 0, 0, 0);
                accL = __builtin_amdgcn_mfma_f32_16x16x32_bf16(aH[kc], bL, accL, 0, 0, 0);
                accL = __builtin_amdgcn_mfma_f32_16x16x32_bf16(aL[kc], bH, accL, 0, 0, 0);
            }
#pragma unroll
            for (int r = 0; r < 4; ++r)
                mean[ctl][r] += fmaxf(accH[r] + accL[r], 0.f);
        }
    }

#pragma unroll
    for (int ctl = 0; ctl < 4; ++ctl) {
        int c = cb * 64 + ctl * 16 + row;
#pragma unroll
        for (int r = 0; r < 4; ++r) {
            int gm = t * 16 + quad * 4 + r;
            out[(size_t)gm * 128 + c] = mean[ctl][r] * (1.f / 16.f);
        }
    }
}

// ---------------- fold for ALL 3 layers ------------------------------------------------
__global__ void fold3_kernel(
    const float* __restrict__ Ws1, const float* __restrict__ Wd1,
    const float* __restrict__ as1, const float* __restrict__ ad1,
    const float* __restrict__ Ws2, const float* __restrict__ Wd2,
    const float* __restrict__ as2, const float* __restrict__ ad2,
    const float* __restrict__ Ws3, const float* __restrict__ Wd3,
    const float* __restrict__ as3, const float* __restrict__ ad3,
    float* __restrict__ fw3)
{
    int gid = blockIdx.x * blockDim.x + threadIdx.x;
    if (gid >= 3 * 4 * 128 * 16) return;
    int l = gid / 8192, rem1 = gid % 8192;
    int f = rem1 / 2048, rem = rem1 % 2048;
    int k = rem >> 4, h = rem & 15;
    int Ntot = (l == 2) ? 512 : 2048;
    int C = Ntot >> 4;
    const float* W;
    const float* a;
    if (l == 0) { W = (f & 1) ? Wd1 : Ws1; a = (f & 1) ? ad1 : as1; }
    else if (l == 1) { W = (f & 1) ? Wd2 : Ws2; a = (f & 1) ? ad2 : as2; }
    else { W = (f & 1) ? Wd3 : Ws3; a = (f & 1) ? ad3 : as3; }
    if (f >= 2) { W += 128 * Ntot; a += 16 * C; }
    float s = 0.f;
    for (int c = 0; c < C; ++c) s += W[(size_t)k * Ntot + h * C + c] * a[h * C + c];
    fw3[gid] = s;
}

// ---------------- score2both: all four folded scores of a layer ------------------------
__global__ __launch_bounds__(256) void score2both_kernel(
    const float* __restrict__ Hd, const float* __restrict__ Hl,
    const float* __restrict__ fw,
    float* __restrict__ ssb0, float* __restrict__ sdb1,
    float* __restrict__ sdb0, float* __restrict__ ssb1)
{
    __shared__ float hs[16 * 128];
    __shared__ float wa[128 * 16];
    __shared__ float wb[128 * 16];
    int b = blockIdx.x;
    const float* Hf; const float* WfA; const float* WfB;
    float* outA; float* outB; int n0;
    if (b < ND / 16) {
        Hf = Hd; WfA = fw; WfB = fw + 3 * 2048; outA = ssb0; outB = sdb1; n0 = b * 16;
    } else {
        Hf = Hl; WfA = fw + 1 * 2048; WfB = fw + 2 * 2048; outA = sdb0; outB = ssb1;
        n0 = (b - ND / 16) * 16;
    }
    int tid = threadIdx.x;
#pragma unroll
    for (int i = 0; i < 8; ++i) {
        int idx = tid + i * 256;
        int nl = idx >> 7, k = idx & 127;
        hs[idx] = Hf[(size_t)(n0 + nl) * 128 + k];
        wa[idx] = WfA[idx];
        wb[idx] = WfB[idx];
    }
    __syncthreads();
    int nl = tid >> 4, h = tid & 15;
    float sa = 0.f, sb = 0.f;
    for (int k = 0; k < 128; ++k) {
        float hv = hs[nl * 128 + k];
        sa += hv * wa[k * 16 + h];
        sb += hv * wb[k * 16 + h];
    }
    int gn = n0 + nl;
    outA[gn * 16 + h] = sa;
    outB[gn * 16 + h] = sb;
}

// ---------------- per-(dst,head) online softmax max/sum, logits inline -----------------
__global__ void ms_kernel(
    const int* __restrict__ esrc, const int* __restrict__ edst,
    const float* __restrict__ ssb0, const float* __restrict__ sdb0,
    const float* __restrict__ ssb1, const float* __restrict__ sdb1,
    const int* __restrict__ offl, const int* __restrict__ csrl, float* __restrict__ msl,
    const int* __restrict__ offd, const int* __restrict__ csrd, float* __restrict__ msd)
{
    int t = blockIdx.x * 256 + threadIdx.x;
    const int* off; const int* csr; const int* srcidx;
    const float* ss; float sdv; float* ms; int d, h;
    if (t < NL * 16) {
        d = t >> 4; h = t & 15;
        off = offl; csr = csrl; srcidx = esrc; ss = ssb0;
        sdv = sdb0[d * 16 + h]; ms = msl;
    } else {
        t -= NL * 16;
        if (t >= ND * 16) return;
        d = t >> 4; h = t & 15;
        off = offd; csr = csrd; srcidx = edst; ss = ssb1;
        sdv = sdb1[d * 16 + h]; ms = msd;
    }
    int e0 = off[d], e1 = off[d + 1];
    float m = -1e30f, s = 0.f;
    for (int e = e0; e < e1; ++e) {
        int sn = srcidx[csr[e]];
        float a = lrelu(ss[sn * 16 + h] + sdv);
        if (a > m) { s = s * __expf(m - a) + 1.f; m = a; }
        else s += __expf(a - m);
    }
    ms[d * 32 + h] = m;
    ms[d * 32 + 16 + h] = s + 1e-16f;
}

// ---------------- CSR build ----------------
__global__ void hist_kernel(const int* __restrict__ esrc, const int* __restrict__ edst,
                            int* __restrict__ degl, int* __restrict__ degd)
{
    int e = blockIdx.x * blockDim.x + threadIdx.x;
    if (e >= NE) return;
    atomicAdd(&degl[edst[e]], 1);
    atomicAdd(&degd[esrc[e]], 1);
}

__global__ __launch_bounds__(1024) void scan2_kernel(
    const int* __restrict__ degA, int* __restrict__ offA, int nA,
    const int* __restrict__ degB, int* __restrict__ offB, int nB)
{
    __shared__ int ps[1024];
    const int* deg = blockIdx.x ? degB : degA;
    int* off = blockIdx.x ? offB : offA;
    int n = blockIdx.x ? nB : nA;
    int tid = threadIdx.x;
    int chunk = (n + 1023) >> 10;
    int start = tid * chunk, end = min(start + chunk, n);
    int p = 0;
    for (int i = start; i < end; ++i) p += deg[i];
    ps[tid] = p;
    __syncthreads();
    for (int o = 1; o < 1024; o <<= 1) {
        int v = (tid >= o) ? ps[tid - o] : 0;
        __syncthreads();
        ps[tid] += v;
        __syncthreads();
    }
    int run = ps[tid] - p;
    for (int i = start; i < end; ++i) { off[i] = run; run += deg[i]; }
    if (tid == 1023) off[n] = ps[1023];
}

__global__ void scatter_kernel(const int* __restrict__ esrc, const int* __restrict__ edst,
                               const int* __restrict__ offl, const int* __restrict__ offd,
                               int* __restrict__ curl, int* __restrict__ curd,
                               int* __restrict__ csrl, int* __restrict__ csrd)
{
    int e = blockIdx.x * blockDim.x + threadIdx.x;
    if (e >= NE) return;
    int dl = edst[e]; int p = atomicAdd(&curl[dl], 1); csrl[offl[dl] + p] = e;
    int dd = esrc[e]; int q = atomicAdd(&curd[dd], 1); csrd[offd[dd] + q] = e;
}

// ---------------- fused alpha + per-head aggregation (BOTH directions, packed u32 out) -
__global__ __launch_bounds__(256) void hagg2_kernel(
    const float* __restrict__ hd, const float* __restrict__ hl,
    const float* __restrict__ ssb0, const float* __restrict__ sdb0, const float* __restrict__ msl,
    const float* __restrict__ ssb1, const float* __restrict__ sdb1, const float* __restrict__ msd,
    const int* __restrict__ offl, const int* __restrict__ csrl,
    const int* __restrict__ offd, const int* __restrict__ csrd,
    const int* __restrict__ esrc, const int* __restrict__ edst,
    unsigned int* __restrict__ haggPl, unsigned int* __restrict__ haggPd)
{
    __shared__ float alpha_s[2][8][17];
    __shared__ int src_s[2][8];
    const int b = blockIdx.x;
    const int tid = threadIdx.x;

    const float* hsrc; const float* ss; const float* sd; const float* ms;
    const int* off; const int* csr; const int* srcidx; unsigned int* haggP;
    int d0;
    if (b < NL / 2) {
        d0 = b * 2;
        hsrc = hd; ss = ssb0; sd = sdb0; ms = msl;
        off = offl; csr = csrl; srcidx = esrc; haggP = haggPl;
    } else {
        d0 = (b - NL / 2) * 2;
        hsrc = hl; ss = ssb1; sd = sdb1; ms = msd;
        off = offd; csr = csrd; srcidx = edst; haggP = haggPd;
    }

    const int half = tid >> 7;
    const int c = tid & 127;
    const int d = d0 + half;
    const int my_e0 = off[d];
    const int my_deg = off[d + 1] - my_e0;
    const int deg0 = off[d0 + 1] - off[d0];
    const int deg1 = off[d0 + 2] - off[d0 + 1];
    const int degmax = deg0 > deg1 ? deg0 : deg1;
    const int ntrip = (degmax + 7) >> 3;

    float acc[16];
#pragma unroll
    for (int h = 0; h < 16; ++h) acc[h] = 0.f;

    for (int trip = 0; trip < ntrip; ++trip) {
        int ce = trip * 8;
        {
            int ei = c >> 4, h = c & 15;
            if (ce + ei < my_deg) {
                int eid = csr[my_e0 + ce + ei];
                int sn = srcidx[eid];
                float a = lrelu(ss[sn * 16 + h] + sd[d * 16 + h]);
                alpha_s[half][ei][h] = __expf(a - ms[d * 32 + h]) / ms[d * 32 + 16 + h];
                if (h == 0) src_s[half][ei] = sn;
            }
        }
        __syncthreads();
        int nc = min(8, my_deg - ce);
        for (int ei = 0; ei < nc; ++ei) {
            float v = hsrc[(size_t)src_s[half][ei] * 128 + c];
#pragma unroll
            for (int h = 0; h < 16; ++h)
                acc[h] += alpha_s[half][ei][h] * v;
        }
        __syncthreads();
    }

    const int t = d >> 4;
    const int lane8 = ((d & 15) + 16 * ((c >> 3) & 3)) * 8 + (c & 7);
    const int kc = c >> 5;
#pragma unroll
    for (int h = 0; h < 16; ++h) {
        float v = acc[h];
        unsigned short hb = f2bf(v);
        unsigned short lb = f2bf(v - bf2f(hb));
        size_t idx = (((size_t)t * 16 + h) * 4 + kc) * 512 + lane8;
        haggP[idx] = (unsigned int)hb | ((unsigned int)lb << 16);
    }
}

// ---------------- layer 3 merged: wave-per-dst alpha + gather + bias + relu + mean + penalty
__global__ __launch_bounds__(256) void agg32both_kernel(
    const float* __restrict__ zs3d, const float* __restrict__ zs3l,
    const float* __restrict__ ssb0, const float* __restrict__ sdb0, const float* __restrict__ msl,
    const float* __restrict__ ssb1, const float* __restrict__ sdb1, const float* __restrict__ msd,
    const int* __restrict__ offl, const int* __restrict__ csrl,
    const int* __restrict__ offd, const int* __restrict__ csrd,
    const int* __restrict__ esrc, const int* __restrict__ edst,
    const float* __restrict__ bias512,
    const float* __restrict__ pw, const float* __restrict__ pb,
    float* __restrict__ hlp, float* __restrict__ hdp)
{
    int d = blockIdx.x * 4 + (threadIdx.x >> 6);
    if (d >= NL + ND) return;
    const int lane = threadIdx.x & 63;

    const float* zs; const float* ss; const float* sd; const float* ms;
    const int* off; const int* csr; const int* srcidx;
    const float* bias; const float* pwt; const float* pbt; float* out;
    if (d < NL) {
        zs = zs3d; ss = ssb0; sd = sdb0; ms = msl;
        off = offl; csr = csrl; srcidx = esrc;
        bias = bias512; pwt = pw + 32; pbt = pb + 1; out = hlp;
    } else {
        d -= NL;
        zs = zs3l; ss = ssb1; sd = sdb1; ms = msd;
        off = offd; csr = csrd; srcidx = edst;
        bias = bias512 + 512; pwt = pw; pbt = pb; out = hdp;
    }

    const int h = lane >> 2;
    const int c0 = lane * 8;

    const float sdv = sd[d * 16 + h];
    const float mh = ms[d * 32 + h];
    const float sh = ms[d * 32 + 16 + h];
    const int e0 = off[d], e1 = off[d + 1];

    float acc[8] = {};
    for (int e = e0; e < e1; ++e) {
        int sn = srcidx[csr[e]];
        float a = lrelu(ss[sn * 16 + h] + sdv);
        float alpha = __expf(a - mh) / sh;
        const float* zr = zs + (size_t)sn * 512 + c0;
        float4 v0 = *(const float4*)zr;
        float4 v1 = *(const float4*)(zr + 4);
        acc[0] += alpha * v0.x; acc[1] += alpha * v0.y;
        acc[2] += alpha * v0.z; acc[3] += alpha * v0.w;
        acc[4] += alpha * v1.x; acc[5] += alpha * v1.y;
        acc[6] += alpha * v1.z; acc[7] += alpha * v1.w;
    }

#pragma unroll
    for (int i = 0; i < 8; ++i)
        acc[i] = fmaxf(acc[i] + bias[c0 + i], 0.f);

#pragma unroll
    for (int m = 4; m <= 32; m <<= 1)
#pragma unroll
        for (int i = 0; i < 8; ++i)
            acc[i] += __shfl_xor(acc[i], m);

    float hr[8];
#pragma unroll
    for (int i = 0; i < 8; ++i) hr[i] = acc[i] * (1.f / 16.f);

    float p = 0.f;
    const int ko = (lane & 3) * 8;
#pragma unroll
    for (int i = 0; i < 8; ++i) p += hr[i] * pwt[ko + i];
    p += __shfl_xor(p, 1);
    p += __shfl_xor(p, 2);
    float t = expf(p + pbt[0]);

    if (lane < 4) {
        float* op = out + (size_t)d * 32 + lane * 8;
#pragma unroll
        for (int i = 0; i < 8; ++i) op[i] = hr[i] * t;
    }
}

// ---------------- final MLP on label edges ----------------
__global__ __launch_bounds__(256) void mlp_kernel(
    const float* __restrict__ hd, const float* __restrict__ hl,
    const int* __restrict__ ls, const int* __restrict__ ld,
    const float* __restrict__ w1, const float* __restrict__ b1,
    const float* __restrict__ w2, const float* __restrict__ b2,
    float* __restrict__ out, int M)
{
    __shared__ float w1s[64 * 64];
    __shared__ float b1s[64];
    __shared__ float w2s[64];
    int tid = threadIdx.x;
#pragma unroll
    for (int i = 0; i < 16; ++i) w1s[tid + i * 256] = w1[tid + i * 256];
    if (tid < 64) { b1s[tid] = b1[tid]; w2s[tid] = w2[tid]; }
    __syncthreads();
    int m = blockIdx.x * 256 + tid;
    if (m >= M) return;
    float f[64];
    const float* hp = hd + (size_t)ls[m] * 32;
    const float* lp = hl + (size_t)ld[m] * 32;
#pragma unroll
    for (int c = 0; c < 32; ++c) { f[c] = hp[c]; f[32 + c] = lp[c]; }
    float o = b2[0];
    for (int j = 0; j < 64; ++j) {
        float hj = b1s[j];
#pragma unroll
        for (int k = 0; k < 64; ++k) hj += f[k] * w1s[k * 64 + j];
        hj = fmaxf(hj, 0.f);
        o += hj * w2s[j];
    }
    out[m] = o;
}

extern "C" void kernel_launch(void* const* d_in, const int* in_sizes, int n_in,
                              void* d_out, int out_size, void* d_ws, size_t ws_size,
                              hipStream_t stream)
{
    const float* x_d = (const float*)d_in[0];
    const float* x_l = (const float*)d_in[1];
    const int* node_id_d = (const int*)d_in[2];
    const int* node_id_l = (const int*)d_in[3];
    const int* edge_src = (const int*)d_in[4];
    const int* edge_dst = (const int*)d_in[5];
    const int* label_src = (const int*)d_in[6];
    const int* label_dst = (const int*)d_in[7];
    const float* emb_d = (const float*)d_in[8];
    const float* emb_l = (const float*)d_in[9];
    const float* lin_dw = (const float*)d_in[10];
    const float* lin_db = (const float*)d_in[11];
    const float* lin_lw = (const float*)d_in[12];
    const float* lin_lb = (const float*)d_in[13];
    const float* Ws[3] = {(const float*)d_in[14], (const float*)d_in[19], (const float*)d_in[24]};
    const float* Wd[3] = {(const float*)d_in[15], (const float*)d_in[20], (const float*)d_in[25]};
    const float* as_[3] = {(const float*)d_in[16], (const float*)d_in[21], (const float*)d_in[26]};
    const float* ad_[3] = {(const float*)d_in[17], (const float*)d_in[22], (const float*)d_in[27]};
    const float* bb[3] = {(const float*)d_in[18], (const float*)d_in[23], (const float*)d_in[28]};
    const float* pw = (const float*)d_in[29];
    const float* pb = (const float*)d_in[30];
    const float* fc1w = (const float*)d_in[31];
    const float* fc1b = (const float*)d_in[32];
    const float* fc2w = (const float*)d_in[33];
    const float* fc2b = (const float*)d_in[34];

    char* wsb = (char*)d_ws;
    size_t woff = 0;
    auto carve = [&](size_t bytes) -> void* {
        woff = (woff + 255) & ~(size_t)255;
        void* p = wsb + woff;
        woff += bytes;
        return p;
    };
    float* hdA = (float*)carve((size_t)ND * 128 * 4);
    float* hlA = (float*)carve((size_t)NL * 128 * 4);
    float* hdB = (float*)carve((size_t)ND * 128 * 4);
    float* hlB = (float*)carve((size_t)NL * 128 * 4);
    unsigned int* haggPl = (unsigned int*)carve((size_t)NL * 2048 * 4);  // L3 reuses as zs3d/zs3l
    unsigned int* haggPd = (unsigned int*)carve((size_t)ND * 2048 * 4);
    unsigned short* WtH = (unsigned short*)carve((size_t)2 * 2 * 2048 * 128 * 2);
    unsigned short* WtL = (unsigned short*)carve((size_t)2 * 2 * 2048 * 128 * 2);
    unsigned short* WtH3 = (unsigned short*)carve((size_t)2 * 128 * 512 * 2);
    unsigned short* WtL3 = (unsigned short*)carve((size_t)2 * 128 * 512 * 2);
    unsigned short* WtInH = (unsigned short*)carve((size_t)(53248 + 32768) * 2);
    unsigned short* WtInL = (unsigned short*)carve((size_t)(53248 + 32768) * 2);
    unsigned int* pAd = (unsigned int*)carve((size_t)(ND / 16) * 4 * 512 * 4);
    unsigned int* pAl = (unsigned int*)carve((size_t)(NL / 16) * 4 * 512 * 4);
    float* ssb0 = (float*)carve((size_t)ND * 16 * 4);
    float* sdb0 = (float*)carve((size_t)NL * 16 * 4);
    float* ssb1 = (float*)carve((size_t)NL * 16 * 4);
    float* sdb1 = (float*)carve((size_t)ND * 16 * 4);
    float* msl = (float*)carve((size_t)NL * 32 * 4);
    float* msd = (float*)carve((size_t)ND * 32 * 4);
    float* fw3 = (float*)carve((size_t)3 * 4 * 2048 * 4);
    int* degl = (int*)carve((size_t)(2 * (NL + ND)) * 4);
    int* degd = degl + NL;
    int* curl = degd + ND;
    int* curd = curl + NL;
    int* offl = (int*)carve((size_t)(NL + 1) * 4);
    int* offd = (int*)carve((size_t)(ND + 1) * 4);
    int* csrl = (int*)carve((size_t)NE * 4);
    int* csrd = (int*)carve((size_t)NE * 4);
    float* hdp = (float*)carve((size_t)ND * 32 * 4);
    float* hlp = (float*)carve((size_t)NL * 32 * 4);

    hipMemsetAsync(degl, 0, (size_t)2 * (NL + ND) * 4, stream);

    hist_kernel<<<(NE + 255) / 256, 256, 0, stream>>>(edge_src, edge_dst, degl, degd);
    scan2_kernel<<<2, 1024, 0, stream>>>(degl, offl, NL, degd, offd, ND);
    scatter_kernel<<<(NE + 255) / 256, 256, 0, stream>>>(edge_src, edge_dst, offl, offd, curl, curd, csrl, csrd);

    fold3_kernel<<<(3 * 8192 + 255) / 256, 256, 0, stream>>>(
        Ws[0], Wd[0], as_[0], ad_[0], Ws[1], Wd[1], as_[1], ad_[1],
        Ws[2], Wd[2], as_[2], ad_[2], fw3);
    wt2_kernel<<<(2 * 524288 + 255) / 256, 256, 0, stream>>>(Ws[0], Ws[1], WtH, WtL);
    wt3_kernel<<<(2 * 65536 + 255) / 256, 256, 0, stream>>>(Ws[2], WtH3, WtL3);
    wtin_kernel<<<(53248 + 32768 + 255) / 256, 256, 0, stream>>>(lin_dw, lin_lw, WtInH, WtInL);

    inlinm_kernel<<<(125 + 250) * 2, 256, 0, stream>>>(
        x_d, x_l, WtInH, WtInL, lin_db, lin_lb, emb_d, emb_l,
        node_id_d, node_id_l, hdA, hlA);

    float* hd_cur = hdA; float* hd_nxt = hdB;
    float* hl_cur = hlA; float* hl_nxt = hlB;

    const int grid_ms = ((NL + ND) * 16 + 255) / 256;

    // ---- layers 1-2: aggregate-then-project, both directions merged per stage ----
    for (int L = 0; L < 2; ++L) {
        const float* fw = fw3 + (size_t)L * 8192;
        const unsigned short* wtH = WtH + (size_t)L * 524288;
        const unsigned short* wtL = WtL + (size_t)L * 524288;

        score2both_kernel<<<ND / 16 + NL / 16, 256, 0, stream>>>(
            hd_cur, hl_cur, fw, ssb0, sdb1, sdb0, ssb1);
        ms_kernel<<<grid_ms, 256, 0, stream>>>(edge_src, edge_dst, ssb0, sdb0, ssb1, sdb1,
                                               offl, csrl, msl, offd, csrd, msd);

        hagg2_kernel<<<NL / 2 + ND / 2, 256, 0, stream>>>(
            hd_cur, hl_cur, ssb0, sdb0, msl, ssb1, sdb1, msd,
            offl, csrl, offd, csrd, edge_src, edge_dst, haggPl, haggPd);

        gemm2r_kernel<<<750, 256, 0, stream>>>(
            haggPl, haggPd, wtH, wtL, bb[L], hl_nxt, hd_nxt);

        float* t;
        t = hd_cur; hd_cur = hd_nxt; hd_nxt = t;
        t = hl_cur; hl_cur = hl_nxt; hl_nxt = t;
    }

    // ---- layer 3: project-then-aggregate (split-bf16 MFMA), merged dispatches ----
    {
        const float* fw = fw3 + 2 * 8192;
        float* zs3d = (float*)haggPl;
        float* zs3l = (float*)haggPl + (size_t)ND * 512;
        score2both_kernel<<<ND / 16 + NL / 16, 256, 0, stream>>>(
            hd_cur, hl_cur, fw, ssb0, sdb1, sdb0, ssb1);
        ms_kernel<<<grid_ms, 256, 0, stream>>>(edge_src, edge_dst, ssb0, sdb0, ssb1, sdb1,
                                               offl, csrl, msl, offd, csrd, msd);

        pack3_kernel<<<((ND + NL) * 128 + 255) / 256, 256, 0, stream>>>(
            hd_cur, hl_cur, pAd, pAl);
        gemm3m_kernel<<<(125 + 250) * 2, 256, 0, stream>>>(
            pAd, pAl, WtH3, WtL3, zs3d, zs3l);

        agg32both_kernel<<<(NL + ND + 3) / 4, 256, 0, stream>>>(
            zs3d, zs3l, ssb0, sdb0, msl, ssb1, sdb1, msd,
            offl, csrl, offd, csrd, edge_src, edge_dst,
            bb[2], pw, pb, hlp, hdp);
    }

    mlp_kernel<<<(NM + 255) / 256, 256, 0, stream>>>(hdp, hlp, label_src, label_dst,
                                                     fc1w, fc1b, fc2w, fc2b, (float*)d_out, NM);
}

// Round 19
// 622.652 us; speedup vs baseline: 1.0756x; 1.0756x over previous
//
#include <hip/hip_runtime.h>
#include <cstdint>
#include <cstddef>

#define ND 8000
#define NL 16000
#define NE 60000
#define NM 50000

typedef __attribute__((ext_vector_type(8))) short bf16x8;
typedef __attribute__((ext_vector_type(4))) float f32x4;
typedef __attribute__((ext_vector_type(8))) unsigned int u32x8;

__device__ __forceinline__ unsigned short f2bf(float x) {
    unsigned int u = __float_as_uint(x);
    unsigned int r = (u + 0x7FFFu + ((u >> 16) & 1u)) >> 16;
    return (unsigned short)r;
}
__device__ __forceinline__ float bf2f(unsigned short b) {
    return __uint_as_float(((unsigned int)b) << 16);
}
__device__ __forceinline__ float lrelu(float x) {
    return x >= 0.f ? x : 0.2f * x;
}

// async global->LDS 16B copy (per-lane global src addr, LDS dest = uniform base + lane*16)
__device__ __forceinline__ void gl_lds16(const void* g, void* l) {
    __builtin_amdgcn_global_load_lds(
        (const __attribute__((address_space(1))) void*)g,
        (__attribute__((address_space(3))) void*)l, 16, 0, 0);
}

// ---------------- input-linear weight pack: split-bf16 B-fragments, K zero-padded ------
__global__ void wtin_kernel(const float* __restrict__ Wd, const float* __restrict__ Wl,
                            unsigned short* __restrict__ WinH, unsigned short* __restrict__ WinL)
{
    int gid = blockIdx.x * 256 + threadIdx.x;
    if (gid >= 53248 + 32768) return;
    const float* W; int K, KC; unsigned short* oH; unsigned short* oL; int rem;
    if (gid < 53248) { W = Wd; K = 412; KC = 13; rem = gid; oH = WinH; oL = WinL; }
    else { W = Wl; K = 240; KC = 8; rem = gid - 53248; oH = WinH + 53248; oL = WinL + 53248; }
    int k = rem >> 7, n = rem & 127;
    float v = (k < K) ? W[(size_t)k * 128 + n] : 0.f;
    unsigned short hb = f2bf(v);
    unsigned short lb = f2bf(v - bf2f(hb));
    int u = n >> 4;
    int kc = k >> 5;
    int lane = (n & 15) + 16 * ((k >> 3) & 3);
    size_t o = ((size_t)u * KC + kc) * 512 + lane * 8 + (k & 7);
    oH[o] = hb;
    oL[o] = lb;
}

// ---------------- fused input linears via split-bf16 MFMA (direct A loads) -------------
__global__ __launch_bounds__(256) void inlinm_kernel(
    const float* __restrict__ x_d, const float* __restrict__ x_l,
    const unsigned short* __restrict__ WinH, const unsigned short* __restrict__ WinL,
    const float* __restrict__ bd, const float* __restrict__ bl,
    const float* __restrict__ embd, const float* __restrict__ embl,
    const int* __restrict__ nidd, const int* __restrict__ nidl,
    float* __restrict__ hd, float* __restrict__ hl)
{
    const int tid = threadIdx.x;
    const int wave = tid >> 6;
    const int lane = tid & 63;
    const int i = blockIdx.x;
    const int cb = i & 1;
    int mt = i >> 1;
    const float* X; int K, KC;
    const unsigned short* wH; const unsigned short* wL;
    const float* bias; const float* emb; const int* nid; float* out;
    if (mt < 125) {
        X = x_d; K = 412; KC = 13; wH = WinH; wL = WinL;
        bias = bd; emb = embd; nid = nidd; out = hd;
    } else {
        mt -= 125;
        X = x_l; K = 240; KC = 8; wH = WinH + 53248; wL = WinL + 53248;
        bias = bl; emb = embl; nid = nidl; out = hl;
    }
    const int m0 = mt * 64 + wave * 16;
    const int row = lane & 15;
    const int quad = lane >> 4;

    f32x4 accH[4] = {};
    f32x4 accL[4] = {};

    const float* xr = X + (size_t)(m0 + row) * K;
    for (int kc = 0; kc < KC; ++kc) {
        int k0 = kc * 32 + quad * 8;
        float xv[8];
        if (k0 + 8 <= K) {
            float4 v0 = *(const float4*)(xr + k0);
            float4 v1 = *(const float4*)(xr + k0 + 4);
            xv[0] = v0.x; xv[1] = v0.y; xv[2] = v0.z; xv[3] = v0.w;
            xv[4] = v1.x; xv[5] = v1.y; xv[6] = v1.z; xv[7] = v1.w;
        } else {
#pragma unroll
            for (int j = 0; j < 8; ++j)
                xv[j] = (k0 + j < K) ? xr[k0 + j] : 0.f;
        }
        bf16x8 aH, aL;
#pragma unroll
        for (int j = 0; j < 8; ++j) {
            unsigned short hb = f2bf(xv[j]);
            aH[j] = (short)hb;
            aL[j] = (short)f2bf(xv[j] - bf2f(hb));
        }
#pragma unroll
        for (int u = 0; u < 4; ++u) {
            int ug = cb * 4 + u;
            size_t boff = ((size_t)ug * KC + kc) * 512 + lane * 8;
            bf16x8 bH = *(const bf16x8*)(wH + boff);
            bf16x8 bL = *(const bf16x8*)(wL + boff);
            accH[u] = __builtin_amdgcn_mfma_f32_16x16x32_bf16(aH, bH, accH[u], 0, 0, 0);
            accL[u] = __builtin_amdgcn_mfma_f32_16x16x32_bf16(aH, bL, accL[u], 0, 0, 0);
            accL[u] = __builtin_amdgcn_mfma_f32_16x16x32_bf16(aL, bH, accL[u], 0, 0, 0);
        }
    }
#pragma unroll
    for (int r = 0; r < 4; ++r) {
        int gm = m0 + quad * 4 + r;
        const float* ep = emb + (size_t)nid[gm] * 128;
        float* op = out + (size_t)gm * 128;
#pragma unroll
        for (int u = 0; u < 4; ++u) {
            int gn = (cb * 4 + u) * 16 + row;
            op[gn] = accH[u][r] + accL[u][r] + bias[gn] + ep[gn];
        }
    }
}

// ---------------- W transpose + split-bf16 into MFMA-fragment tiling, layers 1-2 -------
__global__ void wt2_kernel(const float* __restrict__ W0, const float* __restrict__ W1,
                           unsigned short* __restrict__ WtH, unsigned short* __restrict__ WtL)
{
    int gid = blockIdx.x * 256 + threadIdx.x;
    if (gid >= 2 * 2 * 128 * 2048) return;
    int l = gid >> 19;
    int rem0 = gid & 524287;
    int dir = rem0 >> 18;
    int rem = rem0 & 262143;
    int k = rem >> 11, n = rem & 2047;
    const float* W = l ? W1 : W0;
    float v = W[(size_t)dir * 262144 + (size_t)k * 2048 + n];
    unsigned short hb = f2bf(v);
    unsigned short lb = f2bf(v - bf2f(hb));
    int u = n >> 4;
    int lane = (n & 15) + 16 * ((k >> 3) & 3);
    size_t o = (size_t)l * 524288 + (size_t)dir * 262144 +
               ((size_t)u * 4 + (k >> 5)) * 512 + lane * 8 + (k & 7);
    WtH[o] = hb;
    WtL[o] = lb;
}

// ---------------- W3 split-bf16 fragment pack (layer 3, [2,128,512]) -------------------
__global__ void wt3_kernel(const float* __restrict__ W3,
                           unsigned short* __restrict__ WtH3, unsigned short* __restrict__ WtL3)
{
    int gid = blockIdx.x * 256 + threadIdx.x;
    if (gid >= 2 * 128 * 512) return;
    int dir = gid >> 16;
    int rem = gid & 65535;
    int k = rem >> 9, n = rem & 511;
    float v = W3[(size_t)dir * 65536 + (size_t)k * 512 + n];
    unsigned short hb = f2bf(v);
    unsigned short lb = f2bf(v - bf2f(hb));
    int u = n >> 4;
    int lane = (n & 15) + 16 * ((k >> 3) & 3);
    size_t o = (size_t)dir * 65536 + ((size_t)u * 4 + (k >> 5)) * 512 + lane * 8 + (k & 7);
    WtH3[o] = hb;
    WtL3[o] = lb;
}

// ---------------- pack hd/hl (fp32 [M,128]) -> split-bf16 A-fragment layout ------------
__global__ void pack3_kernel(const float* __restrict__ hd, const float* __restrict__ hl,
                             unsigned int* __restrict__ pAd, unsigned int* __restrict__ pAl)
{
    int gid = blockIdx.x * 256 + threadIdx.x;
    if (gid >= (ND + NL) * 128) return;
    int row = gid >> 7, k = gid & 127;
    const float* src; unsigned int* dst; int gm;
    if (row < ND) { src = hd; dst = pAd; gm = row; }
    else { src = hl; dst = pAl; gm = row - ND; }
    float v = src[(size_t)gm * 128 + k];
    unsigned short hb = f2bf(v);
    unsigned short lb = f2bf(v - bf2f(hb));
    int t = gm >> 4;
    int lane8 = ((gm & 15) + 16 * ((k >> 3) & 3)) * 8 + (k & 7);
    size_t idx = ((size_t)t * 4 + (k >> 5)) * 512 + lane8;
    dst[idx] = (unsigned int)hb | ((unsigned int)lb << 16);
}

// ---------------- layer-3 GEMM via split-bf16 MFMA: zs = h @ W3 ------------------------
__global__ __launch_bounds__(256) void gemm3m_kernel(
    const unsigned int* __restrict__ pAd, const unsigned int* __restrict__ pAl,
    const unsigned short* __restrict__ WtH3, const unsigned short* __restrict__ WtL3,
    float* __restrict__ zs3d, float* __restrict__ zs3l)
{
    const int tid = threadIdx.x;
    const int wave = tid >> 6;
    const int lane = tid & 63;
    const int cb = blockIdx.x & 1;
    int mt = blockIdx.x >> 1;
    const unsigned int* pA_; const unsigned short* wH; const unsigned short* wL; float* zs;
    if (mt < 125) { pA_ = pAd; wH = WtH3; wL = WtL3; zs = zs3d; }
    else { mt -= 125; pA_ = pAl; wH = WtH3 + 65536; wL = WtL3 + 65536; zs = zs3l; }
    const int m0 = mt * 64 + wave * 16;
    const int t = m0 >> 4;
    const int row = lane & 15;
    const int quad = lane >> 4;

    bf16x8 aH[4], aL[4];
#pragma unroll
    for (int kc = 0; kc < 4; ++kc) {
        u32x8 p = *(const u32x8*)(pA_ + ((size_t)t * 4 + kc) * 512 + lane * 8);
#pragma unroll
        for (int ii = 0; ii < 8; ++ii) {
            aH[kc][ii] = (short)(p[ii] & 0xffffu);
            aL[kc][ii] = (short)(p[ii] >> 16);
        }
    }

#pragma unroll 2
    for (int u = 0; u < 16; ++u) {
        const int ug = cb * 16 + u;
        f32x4 accH = (f32x4){0.f, 0.f, 0.f, 0.f};
        f32x4 accL = (f32x4){0.f, 0.f, 0.f, 0.f};
#pragma unroll
        for (int kc = 0; kc < 4; ++kc) {
            size_t boff = ((size_t)ug * 4 + kc) * 512 + lane * 8;
            bf16x8 bH = *(const bf16x8*)(wH + boff);
            bf16x8 bL = *(const bf16x8*)(wL + boff);
            accH = __builtin_amdgcn_mfma_f32_16x16x32_bf16(aH[kc], bH, accH, 0, 0, 0);
            accL = __builtin_amdgcn_mfma_f32_16x16x32_bf16(aH[kc], bL, accL, 0, 0, 0);
            accL = __builtin_amdgcn_mfma_f32_16x16x32_bf16(aL[kc], bH, accL, 0, 0, 0);
        }
        const int gn = ug * 16 + row;
#pragma unroll
        for (int r = 0; r < 4; ++r) {
            int gm = m0 + quad * 4 + r;
            zs[(size_t)gm * 512 + gn] = accH[r] + accL[r];
        }
    }
}

// ---------------- fused per-head projection + bias + relu + HEAD-MEAN (layers 1-2) ----
// v6 (best measured: 628.9 us total): stage A (the big operand) in LDS shared by all 4
// waves; B (4 MB, L2-resident) streamed per-wave. Block = 4 waves over 32 rows x 2048
// cols; wave w owns column-quarter w. Barriers kept: implicit multi-wave overlap (3
// blocks/CU) covers the stage latency; v9's barrier-free variant regressed (95 us, 124
// VGPR). The 3.07M bank conflicts on the 32B/lane LDS reads measured cheaper than every
// alternative staging layout tried.
__global__ __launch_bounds__(256) void gemm2r_kernel(
    const unsigned int* __restrict__ haggPl, const unsigned int* __restrict__ haggPd,
    const unsigned short* __restrict__ WtHb, const unsigned short* __restrict__ WtLb,
    const float* __restrict__ biasb, float* __restrict__ outl, float* __restrict__ outd)
{
    __shared__ unsigned int As[2][4096];   // 2 bufs x 16 KB (2 tiles x 4 kc x 512 u32)

    const int tid = threadIdx.x;
    const int wave = tid >> 6;     // = column quarter cb
    const int lane = tid & 63;
    const int bid = blockIdx.x;

    const unsigned int* haggP; const unsigned short* wHb; const unsigned short* wLb;
    const float* bias; float* out; int mt;
    if (bid < 500) {               // NL: 500 tiles of 32 rows
        mt = bid; haggP = haggPl; wHb = WtHb; wLb = WtLb; bias = biasb; out = outl;
    } else {                       // ND: 250 tiles of 32 rows
        mt = bid - 500; haggP = haggPd; wHb = WtHb + 262144; wLb = WtLb + 262144;
        bias = biasb + 2048; out = outd;
    }
    const int cb = wave;
    const int t0 = mt * 2;         // first global 16-row tile index
    const int row = lane & 15;
    const int quad = lane >> 4;

    // stage A for head h: both tiles' fragments (16 KB), linear LDS dest
    auto stageA = [&](int h, int b) {
#pragma unroll
        for (int j = 0; j < 4; ++j) {
            int slot = tid + j * 256;            // 0..1023 (16B units)
            int t = slot >> 9;                   // tile 0 or 1 (wave-uniform per j)
            const char* g = (const char*)(haggP + ((size_t)(t0 + t) * 16 + h) * 2048)
                            + (size_t)(slot & 511) * 16;
            char* l = (char*)&As[b][0] + (size_t)slot * 16;
            gl_lds16(g, l);
        }
    };

    f32x4 mean[2][2] = {};   // [tile][ctl]

    stageA(0, 0);
    __syncthreads();   // drains vmcnt(0): stage complete

    int buf = 0;
    for (int h = 0; h < 16; ++h) {
        // prefetch next h's A into the other buffer (completes by next barrier)
        if (h < 15) stageA(h + 1, buf ^ 1);

        // read + unpack both tiles' A fragments from LDS
        bf16x8 aH[2][4], aL[2][4];
#pragma unroll
        for (int t = 0; t < 2; ++t)
#pragma unroll
            for (int kc = 0; kc < 4; ++kc) {
                u32x8 p = *(const u32x8*)&As[buf][t * 2048 + kc * 512 + lane * 8];
#pragma unroll
                for (int ii = 0; ii < 8; ++ii) {
                    aH[t][kc][ii] = (short)(p[ii] & 0xffffu);
                    aL[t][kc][ii] = (short)(p[ii] >> 16);
                }
            }

        // compute this wave's column quarter: B streamed from L2
#pragma unroll
        for (int ctl = 0; ctl < 2; ++ctl) {
            const int u = h * 8 + cb * 2 + ctl;
            float bv = bias[h * 128 + cb * 32 + ctl * 16 + row];
            f32x4 accH0 = (f32x4){bv, bv, bv, bv};
            f32x4 accL0 = (f32x4){0.f, 0.f, 0.f, 0.f};
            f32x4 accH1 = (f32x4){bv, bv, bv, bv};
            f32x4 accL1 = (f32x4){0.f, 0.f, 0.f, 0.f};
#pragma unroll
            for (int kc = 0; kc < 4; ++kc) {
                size_t boff = ((size_t)u * 4 + kc) * 512 + lane * 8;
                bf16x8 bH = *(const bf16x8*)(wHb + boff);
                bf16x8 bL = *(const bf16x8*)(wLb + boff);
                accH0 = __builtin_amdgcn_mfma_f32_16x16x32_bf16(aH[0][kc], bH, accH0, 0, 0, 0);
                accL0 = __builtin_amdgcn_mfma_f32_16x16x32_bf16(aH[0][kc], bL, accL0, 0, 0, 0);
                accL0 = __builtin_amdgcn_mfma_f32_16x16x32_bf16(aL[0][kc], bH, accL0, 0, 0, 0);
                accH1 = __builtin_amdgcn_mfma_f32_16x16x32_bf16(aH[1][kc], bH, accH1, 0, 0, 0);
                accL1 = __builtin_amdgcn_mfma_f32_16x16x32_bf16(aH[1][kc], bL, accL1, 0, 0, 0);
                accL1 = __builtin_amdgcn_mfma_f32_16x16x32_bf16(aL[1][kc], bH, accL1, 0, 0, 0);
            }
#pragma unroll
            for (int r = 0; r < 4; ++r) {
                mean[0][ctl][r] += fmaxf(accH0[r] + accL0[r], 0.f);
                mean[1][ctl][r] += fmaxf(accH1[r] + accL1[r], 0.f);
            }
        }
        __syncthreads();   // all waves done reading buf; stage(h+1) complete
        buf ^= 1;
    }

#pragma unroll
    for (int t = 0; t < 2; ++t)
#pragma unroll
        for (int ctl = 0; ctl < 2; ++ctl) {
            int c = cb * 32 + ctl * 16 + row;
#pragma unroll
            for (int r = 0; r < 4; ++r) {
                int gm = mt * 32 + t * 16 + quad * 4 + r;
                out[(size_t)gm * 128 + c] = mean[t][ctl][r] * (1.f / 16.f);
            }
        }
}

// ---------------- fold for ALL 3 layers ------------------------------------------------
__global__ void fold3_kernel(
    const float* __restrict__ Ws1, const float* __restrict__ Wd1,
    const float* __restrict__ as1, const float* __restrict__ ad1,
    const float* __restrict__ Ws2, const float* __restrict__ Wd2,
    const float* __restrict__ as2, const float* __restrict__ ad2,
    const float* __restrict__ Ws3, const float* __restrict__ Wd3,
    const float* __restrict__ as3, const float* __restrict__ ad3,
    float* __restrict__ fw3)
{
    int gid = blockIdx.x * blockDim.x + threadIdx.x;
    if (gid >= 3 * 4 * 128 * 16) return;
    int l = gid / 8192, rem1 = gid % 8192;
    int f = rem1 / 2048, rem = rem1 % 2048;
    int k = rem >> 4, h = rem & 15;
    int Ntot = (l == 2) ? 512 : 2048;
    int C = Ntot >> 4;
    const float* W;
    const float* a;
    if (l == 0) { W = (f & 1) ? Wd1 : Ws1; a = (f & 1) ? ad1 : as1; }
    else if (l == 1) { W = (f & 1) ? Wd2 : Ws2; a = (f & 1) ? ad2 : as2; }
    else { W = (f & 1) ? Wd3 : Ws3; a = (f & 1) ? ad3 : as3; }
    if (f >= 2) { W += 128 * Ntot; a += 16 * C; }
    float s = 0.f;
    for (int c = 0; c < C; ++c) s += W[(size_t)k * Ntot + h * C + c] * a[h * C + c];
    fw3[gid] = s;
}

// ---------------- score2both: all four folded scores of a layer ------------------------
__global__ __launch_bounds__(256) void score2both_kernel(
    const float* __restrict__ Hd, const float* __restrict__ Hl,
    const float* __restrict__ fw,
    float* __restrict__ ssb0, float* __restrict__ sdb1,
    float* __restrict__ sdb0, float* __restrict__ ssb1)
{
    __shared__ float hs[16 * 128];
    __shared__ float wa[128 * 16];
    __shared__ float wb[128 * 16];
    int b = blockIdx.x;
    const float* Hf; const float* WfA; const float* WfB;
    float* outA; float* outB; int n0;
    if (b < ND / 16) {
        Hf = Hd; WfA = fw; WfB = fw + 3 * 2048; outA = ssb0; outB = sdb1; n0 = b * 16;
    } else {
        Hf = Hl; WfA = fw + 1 * 2048; WfB = fw + 2 * 2048; outA = sdb0; outB = ssb1;
        n0 = (b - ND / 16) * 16;
    }
    int tid = threadIdx.x;
#pragma unroll
    for (int i = 0; i < 8; ++i) {
        int idx = tid + i * 256;
        int nl = idx >> 7, k = idx & 127;
        hs[idx] = Hf[(size_t)(n0 + nl) * 128 + k];
        wa[idx] = WfA[idx];
        wb[idx] = WfB[idx];
    }
    __syncthreads();
    int nl = tid >> 4, h = tid & 15;
    float sa = 0.f, sb = 0.f;
    for (int k = 0; k < 128; ++k) {
        float hv = hs[nl * 128 + k];
        sa += hv * wa[k * 16 + h];
        sb += hv * wb[k * 16 + h];
    }
    int gn = n0 + nl;
    outA[gn * 16 + h] = sa;
    outB[gn * 16 + h] = sb;
}

// ---------------- per-(dst,head) online softmax max/sum, logits inline -----------------
__global__ void ms_kernel(
    const int* __restrict__ esrc, const int* __restrict__ edst,
    const float* __restrict__ ssb0, const float* __restrict__ sdb0,
    const float* __restrict__ ssb1, const float* __restrict__ sdb1,
    const int* __restrict__ offl, const int* __restrict__ csrl, float* __restrict__ msl,
    const int* __restrict__ offd, const int* __restrict__ csrd, float* __restrict__ msd)
{
    int t = blockIdx.x * 256 + threadIdx.x;
    const int* off; const int* csr; const int* srcidx;
    const float* ss; float sdv; float* ms; int d, h;
    if (t < NL * 16) {
        d = t >> 4; h = t & 15;
        off = offl; csr = csrl; srcidx = esrc; ss = ssb0;
        sdv = sdb0[d * 16 + h]; ms = msl;
    } else {
        t -= NL * 16;
        if (t >= ND * 16) return;
        d = t >> 4; h = t & 15;
        off = offd; csr = csrd; srcidx = edst; ss = ssb1;
        sdv = sdb1[d * 16 + h]; ms = msd;
    }
    int e0 = off[d], e1 = off[d + 1];
    float m = -1e30f, s = 0.f;
    for (int e = e0; e < e1; ++e) {
        int sn = srcidx[csr[e]];
        float a = lrelu(ss[sn * 16 + h] + sdv);
        if (a > m) { s = s * __expf(m - a) + 1.f; m = a; }
        else s += __expf(a - m);
    }
    ms[d * 32 + h] = m;
    ms[d * 32 + 16 + h] = s + 1e-16f;
}

// ---------------- CSR build ----------------
__global__ void hist_kernel(const int* __restrict__ esrc, const int* __restrict__ edst,
                            int* __restrict__ degl, int* __restrict__ degd)
{
    int e = blockIdx.x * blockDim.x + threadIdx.x;
    if (e >= NE) return;
    atomicAdd(&degl[edst[e]], 1);
    atomicAdd(&degd[esrc[e]], 1);
}

__global__ __launch_bounds__(1024) void scan2_kernel(
    const int* __restrict__ degA, int* __restrict__ offA, int nA,
    const int* __restrict__ degB, int* __restrict__ offB, int nB)
{
    __shared__ int ps[1024];
    const int* deg = blockIdx.x ? degB : degA;
    int* off = blockIdx.x ? offB : offA;
    int n = blockIdx.x ? nB : nA;
    int tid = threadIdx.x;
    int chunk = (n + 1023) >> 10;
    int start = tid * chunk, end = min(start + chunk, n);
    int p = 0;
    for (int i = start; i < end; ++i) p += deg[i];
    ps[tid] = p;
    __syncthreads();
    for (int o = 1; o < 1024; o <<= 1) {
        int v = (tid >= o) ? ps[tid - o] : 0;
        __syncthreads();
        ps[tid] += v;
        __syncthreads();
    }
    int run = ps[tid] - p;
    for (int i = start; i < end; ++i) { off[i] = run; run += deg[i]; }
    if (tid == 1023) off[n] = ps[1023];
}

__global__ void scatter_kernel(const int* __restrict__ esrc, const int* __restrict__ edst,
                               const int* __restrict__ offl, const int* __restrict__ offd,
                               int* __restrict__ curl, int* __restrict__ curd,
                               int* __restrict__ csrl, int* __restrict__ csrd)
{
    int e = blockIdx.x * blockDim.x + threadIdx.x;
    if (e >= NE) return;
    int dl = edst[e]; int p = atomicAdd(&curl[dl], 1); csrl[offl[dl] + p] = e;
    int dd = esrc[e]; int q = atomicAdd(&curd[dd], 1); csrd[offd[dd] + q] = e;
}

// ---------------- fused alpha + per-head aggregation (BOTH directions, one dispatch) ---
__global__ __launch_bounds__(256) void hagg2_kernel(
    const float* __restrict__ hd, const float* __restrict__ hl,
    const float* __restrict__ ssb0, const float* __restrict__ sdb0, const float* __restrict__ msl,
    const float* __restrict__ ssb1, const float* __restrict__ sdb1, const float* __restrict__ msd,
    const int* __restrict__ offl, const int* __restrict__ csrl,
    const int* __restrict__ offd, const int* __restrict__ csrd,
    const int* __restrict__ esrc, const int* __restrict__ edst,
    unsigned int* __restrict__ haggPl, unsigned int* __restrict__ haggPd)
{
    __shared__ float alpha_s[2][8][17];
    __shared__ int src_s[2][8];
    const int b = blockIdx.x;
    const int tid = threadIdx.x;

    const float* hsrc; const float* ss; const float* sd; const float* ms;
    const int* off; const int* csr; const int* srcidx; unsigned int* haggP;
    int d0;
    if (b < NL / 2) {
        d0 = b * 2;
        hsrc = hd; ss = ssb0; sd = sdb0; ms = msl;
        off = offl; csr = csrl; srcidx = esrc; haggP = haggPl;
    } else {
        d0 = (b - NL / 2) * 2;
        hsrc = hl; ss = ssb1; sd = sdb1; ms = msd;
        off = offd; csr = csrd; srcidx = edst; haggP = haggPd;
    }

    const int half = tid >> 7;
    const int c = tid & 127;
    const int d = d0 + half;
    const int my_e0 = off[d];
    const int my_deg = off[d + 1] - my_e0;
    const int deg0 = off[d0 + 1] - off[d0];
    const int deg1 = off[d0 + 2] - off[d0 + 1];
    const int degmax = deg0 > deg1 ? deg0 : deg1;
    const int ntrip = (degmax + 7) >> 3;

    float acc[16];
#pragma unroll
    for (int h = 0; h < 16; ++h) acc[h] = 0.f;

    for (int trip = 0; trip < ntrip; ++trip) {
        int ce = trip * 8;
        {
            int ei = c >> 4, h = c & 15;
            if (ce + ei < my_deg) {
                int eid = csr[my_e0 + ce + ei];
                int sn = srcidx[eid];
                float a = lrelu(ss[sn * 16 + h] + sd[d * 16 + h]);
                alpha_s[half][ei][h] = __expf(a - ms[d * 32 + h]) / ms[d * 32 + 16 + h];
                if (h == 0) src_s[half][ei] = sn;
            }
        }
        __syncthreads();
        int nc = min(8, my_deg - ce);
        for (int ei = 0; ei < nc; ++ei) {
            float v = hsrc[(size_t)src_s[half][ei] * 128 + c];
#pragma unroll
            for (int h = 0; h < 16; ++h)
                acc[h] += alpha_s[half][ei][h] * v;
        }
        __syncthreads();
    }

    const int t = d >> 4;
    const int lane8 = ((d & 15) + 16 * ((c >> 3) & 3)) * 8 + (c & 7);
    const int kc = c >> 5;
#pragma unroll
    for (int h = 0; h < 16; ++h) {
        float v = acc[h];
        unsigned short hb = f2bf(v);
        unsigned short lb = f2bf(v - bf2f(hb));
        size_t idx = (((size_t)t * 16 + h) * 4 + kc) * 512 + lane8;
        haggP[idx] = (unsigned int)hb | ((unsigned int)lb << 16);
    }
}

// ---------------- layer 3 merged: wave-per-dst alpha + gather + bias + relu + mean + penalty
__global__ __launch_bounds__(256) void agg32both_kernel(
    const float* __restrict__ zs3d, const float* __restrict__ zs3l,
    const float* __restrict__ ssb0, const float* __restrict__ sdb0, const float* __restrict__ msl,
    const float* __restrict__ ssb1, const float* __restrict__ sdb1, const float* __restrict__ msd,
    const int* __restrict__ offl, const int* __restrict__ csrl,
    const int* __restrict__ offd, const int* __restrict__ csrd,
    const int* __restrict__ esrc, const int* __restrict__ edst,
    const float* __restrict__ bias512,
    const float* __restrict__ pw, const float* __restrict__ pb,
    float* __restrict__ hlp, float* __restrict__ hdp)
{
    int d = blockIdx.x * 4 + (threadIdx.x >> 6);
    if (d >= NL + ND) return;
    const int lane = threadIdx.x & 63;

    const float* zs; const float* ss; const float* sd; const float* ms;
    const int* off; const int* csr; const int* srcidx;
    const float* bias; const float* pwt; const float* pbt; float* out;
    if (d < NL) {
        zs = zs3d; ss = ssb0; sd = sdb0; ms = msl;
        off = offl; csr = csrl; srcidx = esrc;
        bias = bias512; pwt = pw + 32; pbt = pb + 1; out = hlp;
    } else {
        d -= NL;
        zs = zs3l; ss = ssb1; sd = sdb1; ms = msd;
        off = offd; csr = csrd; srcidx = edst;
        bias = bias512 + 512; pwt = pw; pbt = pb; out = hdp;
    }

    const int h = lane >> 2;
    const int c0 = lane * 8;

    const float sdv = sd[d * 16 + h];
    const float mh = ms[d * 32 + h];
    const float sh = ms[d * 32 + 16 + h];
    const int e0 = off[d], e1 = off[d + 1];

    float acc[8] = {};
    for (int e = e0; e < e1; ++e) {
        int sn = srcidx[csr[e]];
        float a = lrelu(ss[sn * 16 + h] + sdv);
        float alpha = __expf(a - mh) / sh;
        const float* zr = zs + (size_t)sn * 512 + c0;
        float4 v0 = *(const float4*)zr;
        float4 v1 = *(const float4*)(zr + 4);
        acc[0] += alpha * v0.x; acc[1] += alpha * v0.y;
        acc[2] += alpha * v0.z; acc[3] += alpha * v0.w;
        acc[4] += alpha * v1.x; acc[5] += alpha * v1.y;
        acc[6] += alpha * v1.z; acc[7] += alpha * v1.w;
    }

#pragma unroll
    for (int i = 0; i < 8; ++i)
        acc[i] = fmaxf(acc[i] + bias[c0 + i], 0.f);

#pragma unroll
    for (int m = 4; m <= 32; m <<= 1)
#pragma unroll
        for (int i = 0; i < 8; ++i)
            acc[i] += __shfl_xor(acc[i], m);

    float hr[8];
#pragma unroll
    for (int i = 0; i < 8; ++i) hr[i] = acc[i] * (1.f / 16.f);

    float p = 0.f;
    const int ko = (lane & 3) * 8;
#pragma unroll
    for (int i = 0; i < 8; ++i) p += hr[i] * pwt[ko + i];
    p += __shfl_xor(p, 1);
    p += __shfl_xor(p, 2);
    float t = expf(p + pbt[0]);

    if (lane < 4) {
        float* op = out + (size_t)d * 32 + lane * 8;
#pragma unroll
        for (int i = 0; i < 8; ++i) op[i] = hr[i] * t;
    }
}

// ---------------- final MLP on label edges ----------------
__global__ __launch_bounds__(256) void mlp_kernel(
    const float* __restrict__ hd, const float* __restrict__ hl,
    const int* __restrict__ ls, const int* __restrict__ ld,
    const float* __restrict__ w1, const float* __restrict__ b1,
    const float* __restrict__ w2, const float* __restrict__ b2,
    float* __restrict__ out, int M)
{
    __shared__ float w1s[64 * 64];
    __shared__ float b1s[64];
    __shared__ float w2s[64];
    int tid = threadIdx.x;
#pragma unroll
    for (int i = 0; i < 16; ++i) w1s[tid + i * 256] = w1[tid + i * 256];
    if (tid < 64) { b1s[tid] = b1[tid]; w2s[tid] = w2[tid]; }
    __syncthreads();
    int m = blockIdx.x * 256 + tid;
    if (m >= M) return;
    float f[64];
    const float* hp = hd + (size_t)ls[m] * 32;
    const float* lp = hl + (size_t)ld[m] * 32;
#pragma unroll
    for (int c = 0; c < 32; ++c) { f[c] = hp[c]; f[32 + c] = lp[c]; }
    float o = b2[0];
    for (int j = 0; j < 64; ++j) {
        float hj = b1s[j];
#pragma unroll
        for (int k = 0; k < 64; ++k) hj += f[k] * w1s[k * 64 + j];
        hj = fmaxf(hj, 0.f);
        o += hj * w2s[j];
    }
    out[m] = o;
}

extern "C" void kernel_launch(void* const* d_in, const int* in_sizes, int n_in,
                              void* d_out, int out_size, void* d_ws, size_t ws_size,
                              hipStream_t stream)
{
    const float* x_d = (const float*)d_in[0];
    const float* x_l = (const float*)d_in[1];
    const int* node_id_d = (const int*)d_in[2];
    const int* node_id_l = (const int*)d_in[3];
    const int* edge_src = (const int*)d_in[4];
    const int* edge_dst = (const int*)d_in[5];
    const int* label_src = (const int*)d_in[6];
    const int* label_dst = (const int*)d_in[7];
    const float* emb_d = (const float*)d_in[8];
    const float* emb_l = (const float*)d_in[9];
    const float* lin_dw = (const float*)d_in[10];
    const float* lin_db = (const float*)d_in[11];
    const float* lin_lw = (const float*)d_in[12];
    const float* lin_lb = (const float*)d_in[13];
    const float* Ws[3] = {(const float*)d_in[14], (const float*)d_in[19], (const float*)d_in[24]};
    const float* Wd[3] = {(const float*)d_in[15], (const float*)d_in[20], (const float*)d_in[25]};
    const float* as_[3] = {(const float*)d_in[16], (const float*)d_in[21], (const float*)d_in[26]};
    const float* ad_[3] = {(const float*)d_in[17], (const float*)d_in[22], (const float*)d_in[27]};
    const float* bb[3] = {(const float*)d_in[18], (const float*)d_in[23], (const float*)d_in[28]};
    const float* pw = (const float*)d_in[29];
    const float* pb = (const float*)d_in[30];
    const float* fc1w = (const float*)d_in[31];
    const float* fc1b = (const float*)d_in[32];
    const float* fc2w = (const float*)d_in[33];
    const float* fc2b = (const float*)d_in[34];

    char* wsb = (char*)d_ws;
    size_t woff = 0;
    auto carve = [&](size_t bytes) -> void* {
        woff = (woff + 255) & ~(size_t)255;
        void* p = wsb + woff;
        woff += bytes;
        return p;
    };
    float* hdA = (float*)carve((size_t)ND * 128 * 4);
    float* hlA = (float*)carve((size_t)NL * 128 * 4);
    float* hdB = (float*)carve((size_t)ND * 128 * 4);
    float* hlB = (float*)carve((size_t)NL * 128 * 4);
    unsigned int* haggPl = (unsigned int*)carve((size_t)NL * 2048 * 4);  // L3 reuses as zs3d/zs3l
    unsigned int* haggPd = (unsigned int*)carve((size_t)ND * 2048 * 4);
    unsigned short* WtH = (unsigned short*)carve((size_t)2 * 2 * 2048 * 128 * 2);
    unsigned short* WtL = (unsigned short*)carve((size_t)2 * 2 * 2048 * 128 * 2);
    unsigned short* WtH3 = (unsigned short*)carve((size_t)2 * 128 * 512 * 2);
    unsigned short* WtL3 = (unsigned short*)carve((size_t)2 * 128 * 512 * 2);
    unsigned short* WtInH = (unsigned short*)carve((size_t)(53248 + 32768) * 2);
    unsigned short* WtInL = (unsigned short*)carve((size_t)(53248 + 32768) * 2);
    unsigned int* pAd = (unsigned int*)carve((size_t)(ND / 16) * 4 * 512 * 4);
    unsigned int* pAl = (unsigned int*)carve((size_t)(NL / 16) * 4 * 512 * 4);
    float* ssb0 = (float*)carve((size_t)ND * 16 * 4);
    float* sdb0 = (float*)carve((size_t)NL * 16 * 4);
    float* ssb1 = (float*)carve((size_t)NL * 16 * 4);
    float* sdb1 = (float*)carve((size_t)ND * 16 * 4);
    float* msl = (float*)carve((size_t)NL * 32 * 4);
    float* msd = (float*)carve((size_t)ND * 32 * 4);
    float* fw3 = (float*)carve((size_t)3 * 4 * 2048 * 4);
    int* degl = (int*)carve((size_t)(2 * (NL + ND)) * 4);
    int* degd = degl + NL;
    int* curl = degd + ND;
    int* curd = curl + NL;
    int* offl = (int*)carve((size_t)(NL + 1) * 4);
    int* offd = (int*)carve((size_t)(ND + 1) * 4);
    int* csrl = (int*)carve((size_t)NE * 4);
    int* csrd = (int*)carve((size_t)NE * 4);
    float* hdp = (float*)carve((size_t)ND * 32 * 4);
    float* hlp = (float*)carve((size_t)NL * 32 * 4);

    hipMemsetAsync(degl, 0, (size_t)2 * (NL + ND) * 4, stream);

    hist_kernel<<<(NE + 255) / 256, 256, 0, stream>>>(edge_src, edge_dst, degl, degd);
    scan2_kernel<<<2, 1024, 0, stream>>>(degl, offl, NL, degd, offd, ND);
    scatter_kernel<<<(NE + 255) / 256, 256, 0, stream>>>(edge_src, edge_dst, offl, offd, curl, curd, csrl, csrd);

    fold3_kernel<<<(3 * 8192 + 255) / 256, 256, 0, stream>>>(
        Ws[0], Wd[0], as_[0], ad_[0], Ws[1], Wd[1], as_[1], ad_[1],
        Ws[2], Wd[2], as_[2], ad_[2], fw3);
    wt2_kernel<<<(2 * 524288 + 255) / 256, 256, 0, stream>>>(Ws[0], Ws[1], WtH, WtL);
    wt3_kernel<<<(2 * 65536 + 255) / 256, 256, 0, stream>>>(Ws[2], WtH3, WtL3);
    wtin_kernel<<<(53248 + 32768 + 255) / 256, 256, 0, stream>>>(lin_dw, lin_lw, WtInH, WtInL);

    inlinm_kernel<<<(125 + 250) * 2, 256, 0, stream>>>(
        x_d, x_l, WtInH, WtInL, lin_db, lin_lb, emb_d, emb_l,
        node_id_d, node_id_l, hdA, hlA);

    float* hd_cur = hdA; float* hd_nxt = hdB;
    float* hl_cur = hlA; float* hl_nxt = hlB;

    const int grid_ms = ((NL + ND) * 16 + 255) / 256;

    // ---- layers 1-2: aggregate-then-project, both directions merged per stage ----
    for (int L = 0; L < 2; ++L) {
        const float* fw = fw3 + (size_t)L * 8192;
        const unsigned short* wtH = WtH + (size_t)L * 524288;
        const unsigned short* wtL = WtL + (size_t)L * 524288;

        score2both_kernel<<<ND / 16 + NL / 16, 256, 0, stream>>>(
            hd_cur, hl_cur, fw, ssb0, sdb1, sdb0, ssb1);
        ms_kernel<<<grid_ms, 256, 0, stream>>>(edge_src, edge_dst, ssb0, sdb0, ssb1, sdb1,
                                               offl, csrl, msl, offd, csrd, msd);

        hagg2_kernel<<<NL / 2 + ND / 2, 256, 0, stream>>>(
            hd_cur, hl_cur, ssb0, sdb0, msl, ssb1, sdb1, msd,
            offl, csrl, offd, csrd, edge_src, edge_dst, haggPl, haggPd);

        gemm2r_kernel<<<500 + 250, 256, 0, stream>>>(
            haggPl, haggPd, wtH, wtL, bb[L], hl_nxt, hd_nxt);

        float* t;
        t = hd_cur; hd_cur = hd_nxt; hd_nxt = t;
        t = hl_cur; hl_cur = hl_nxt; hl_nxt = t;
    }

    // ---- layer 3: project-then-aggregate (split-bf16 MFMA), merged dispatches ----
    {
        const float* fw = fw3 + 2 * 8192;
        float* zs3d = (float*)haggPl;
        float* zs3l = (float*)haggPl + (size_t)ND * 512;
        score2both_kernel<<<ND / 16 + NL / 16, 256, 0, stream>>>(
            hd_cur, hl_cur, fw, ssb0, sdb1, sdb0, ssb1);
        ms_kernel<<<grid_ms, 256, 0, stream>>>(edge_src, edge_dst, ssb0, sdb0, ssb1, sdb1,
                                               offl, csrl, msl, offd, csrd, msd);

        pack3_kernel<<<((ND + NL) * 128 + 255) / 256, 256, 0, stream>>>(
            hd_cur, hl_cur, pAd, pAl);
        gemm3m_kernel<<<(125 + 250) * 2, 256, 0, stream>>>(
            pAd, pAl, WtH3, WtL3, zs3d, zs3l);

        agg32both_kernel<<<(NL + ND + 3) / 4, 256, 0, stream>>>(
            zs3d, zs3l, ssb0, sdb0, msl, ssb1, sdb1, msd,
            offl, csrl, offd, csrd, edge_src, edge_dst,
            bb[2], pw, pb, hlp, hdp);
    }

    mlp_kernel<<<(NM + 255) / 256, 256, 0, stream>>>(hdp, hlp, label_src, label_dst,
                                                     fc1w, fc1b, fc2w, fc2b, (float*)d_out, NM);
}